// Round 10
// baseline (421.627 us; speedup 1.0000x reference)
//
#include <hip/hip_runtime.h>

typedef __bf16 bf16;
typedef __bf16 bf16x2 __attribute__((ext_vector_type(2)));
typedef __bf16 bf16x4 __attribute__((ext_vector_type(4)));
typedef __bf16 bf16x8 __attribute__((ext_vector_type(8)));
typedef float  f32x4  __attribute__((ext_vector_type(4)));
typedef short  short4v __attribute__((ext_vector_type(4)));

#define S_LEN 1863
#define S_PAD 1920
#define DM 1024
#define NH 16
#define HDIM 64
#define AUGD 160      // 64 qk dims + 32 x-onehot + 32 y-onehot + 32 z-onehot
#define KA_STR 168    // Kaug row stride (336 B): DMA-contiguous AND 2-way-bank-free
#define VT_TILE 4608  // V tile: 64 d-rows x 72 (pad) = 9216 B, 9 DMA segs
#define QKV_STRIDE 3072
#define NQT128 15
#define NT64 30       // 64-row s-tiles
#define CHUNK 4
#define MAXC 8
#define NQMULTI 13    // q-tiles with >1 chunk (qt = 2..14)
#define NCHUNK_HEAD 64
#define NCNT (NH * NQMULTI)

#define MFMA_BF16 __builtin_amdgcn_mfma_f32_16x16x32_bf16
#define MFMA_BF16_K16 __builtin_amdgcn_mfma_f32_16x16x16bf16_1k

__constant__ int QT_BASE[15] = {0, 1, 2, 4, 6, 9, 12, 16, 20, 25, 30, 36, 42, 49, 56};

// async global->LDS copy, 16 B per lane; lds dest = uniform base + lane*16
__device__ __forceinline__ void dma16(const bf16* g, bf16* l) {
  __builtin_amdgcn_global_load_lds(
      (const __attribute__((address_space(1))) unsigned int*)g,
      (__attribute__((address_space(3))) unsigned int*)l, 16, 0, 0);
}

__device__ __forceinline__ short4v as_s4(bf16x4 v) {
  return __builtin_bit_cast(short4v, v);
}

// ---------------------------------------------------------------------------
// fused fp32->bf16 conversion of x, Wqkv, Wout + zeroing of combine counters
// ---------------------------------------------------------------------------
__global__ void cvt3(const float* __restrict__ a, bf16* __restrict__ oa, int na4,
                     const float* __restrict__ b, bf16* __restrict__ ob, int nb4,
                     const float* __restrict__ c, bf16* __restrict__ oc, int nc4,
                     int* __restrict__ Ocnt) {
  if (blockIdx.x == 0 && threadIdx.x < NCNT) Ocnt[threadIdx.x] = 0;
  int j = blockIdx.x * blockDim.x + threadIdx.x;
  const float* s; bf16* d;
  if (j < na4) { s = a; d = oa; }
  else {
    j -= na4;
    if (j < nb4) { s = b; d = ob; }
    else { j -= nb4; if (j >= nc4) return; s = c; d = oc; }
  }
  float4 v = ((const float4*)s)[j];
  bf16x4 o;
  o[0] = (bf16)v.x; o[1] = (bf16)v.y; o[2] = (bf16)v.z; o[3] = (bf16)v.w;
  ((bf16x4*)d)[j] = o;
}

// ---------------------------------------------------------------------------
// bf16 MFMA GEMM, 128x64 tile, BK=32, 4 waves, global_load_lds staging.
// (R8-proven config: 720 blocks for gemm1 -> good CU coverage.)
// ---------------------------------------------------------------------------
template <typename T>
__global__ __launch_bounds__(256) void gemm_bt(const bf16* __restrict__ A,
                                               const bf16* __restrict__ B,
                                               T* __restrict__ C,
                                               int M, int N, int K) {
  __shared__ bf16 As[128][32];
  __shared__ bf16 Bs[64][32];
  const int t = threadIdx.x;
  const int w = t >> 6, l = t & 63;
  const int quad = l >> 4, l16 = l & 15;
  const int wm = w >> 1, wn = w & 1;
  const int bm = blockIdx.y * 128, bn = blockIdx.x * 64;
  const int lr = l >> 2;          // 0..15 row within a 16-row DMA segment
  const int lc = (l & 3) * 8;     // col element offset (16 B per lane)

  f32x4 acc[4][2];
#pragma unroll
  for (int mi = 0; mi < 4; ++mi)
#pragma unroll
    for (int ni = 0; ni < 2; ++ni) acc[mi][ni] = 0;

  for (int k0 = 0; k0 < K; k0 += 32) {
    __syncthreads();
    // A: 8 segments of 16 rows; wave w does segs 2w, 2w+1. B: 4 segs, one/wave.
#pragma unroll
    for (int p = 0; p < 2; ++p) {
      const int seg = 2 * w + p;
      dma16(&A[(size_t)min(bm + seg * 16 + lr, M - 1) * K + k0 + lc], &As[seg * 16][0]);
    }
    dma16(&B[(size_t)(bn + w * 16 + lr) * K + k0 + lc], &Bs[w * 16][0]);
    __syncthreads();

    bf16x8 af[4], bfr[2];
#pragma unroll
    for (int mi = 0; mi < 4; ++mi) af[mi]  = *(bf16x8*)&As[wm * 64 + mi * 16 + l16][quad * 8];
#pragma unroll
    for (int ni = 0; ni < 2; ++ni) bfr[ni] = *(bf16x8*)&Bs[wn * 32 + ni * 16 + l16][quad * 8];
#pragma unroll
    for (int mi = 0; mi < 4; ++mi)
#pragma unroll
      for (int ni = 0; ni < 2; ++ni)
        acc[mi][ni] = MFMA_BF16(af[mi], bfr[ni], acc[mi][ni], 0, 0, 0);
  }

#pragma unroll
  for (int mi = 0; mi < 4; ++mi)
#pragma unroll
    for (int r = 0; r < 4; ++r) {
      int m = bm + wm * 64 + mi * 16 + quad * 4 + r;
      if (m < M) {
#pragma unroll
        for (int ni = 0; ni < 2; ++ni)
          C[(size_t)m * N + bn + wn * 32 + ni * 16 + l16] = (T)acc[mi][ni][r];
      }
    }
}

// ---------------------------------------------------------------------------
// bf16 MFMA GEMM, 64x64 tile with DMA staging (N=1024 proj; 480 blocks).
// ---------------------------------------------------------------------------
__global__ __launch_bounds__(256) void gemm_bt64(const bf16* __restrict__ A,
                                                 const bf16* __restrict__ B,
                                                 float* __restrict__ C,
                                                 int M, int N, int K) {
  __shared__ bf16 As[64][32];
  __shared__ bf16 Bs[64][32];
  const int t = threadIdx.x;
  const int w = t >> 6, l = t & 63;
  const int quad = l >> 4, l16 = l & 15;
  const int wm = w >> 1, wn = w & 1;
  const int bm = blockIdx.y * 64, bn = blockIdx.x * 64;
  const int lr = l >> 2;
  const int lc = (l & 3) * 8;

  f32x4 acc[2][2];
#pragma unroll
  for (int mi = 0; mi < 2; ++mi)
#pragma unroll
    for (int ni = 0; ni < 2; ++ni) acc[mi][ni] = 0;

  for (int k0 = 0; k0 < K; k0 += 32) {
    __syncthreads();
    dma16(&A[(size_t)min(bm + w * 16 + lr, M - 1) * K + k0 + lc], &As[w * 16][0]);
    dma16(&B[(size_t)(bn + w * 16 + lr) * K + k0 + lc], &Bs[w * 16][0]);
    __syncthreads();

    bf16x8 af[2], bfr[2];
#pragma unroll
    for (int mi = 0; mi < 2; ++mi) af[mi]  = *(bf16x8*)&As[wm * 32 + mi * 16 + l16][quad * 8];
#pragma unroll
    for (int ni = 0; ni < 2; ++ni) bfr[ni] = *(bf16x8*)&Bs[wn * 32 + ni * 16 + l16][quad * 8];
#pragma unroll
    for (int mi = 0; mi < 2; ++mi)
#pragma unroll
      for (int ni = 0; ni < 2; ++ni)
        acc[mi][ni] = MFMA_BF16(af[mi], bfr[ni], acc[mi][ni], 0, 0, 0);
  }

#pragma unroll
  for (int mi = 0; mi < 2; ++mi)
#pragma unroll
    for (int r = 0; r < 4; ++r) {
      int m = bm + wm * 32 + mi * 16 + quad * 4 + r;
      if (m < M) {
#pragma unroll
        for (int ni = 0; ni < 2; ++ni)
          C[(size_t)m * N + bn + wn * 32 + ni * 16 + l16] = acc[mi][ni][r];
      }
    }
}

// ---------------------------------------------------------------------------
// Fused pack: RoPE + bias-augmented Q/K build + V tile-transpose.
// Vt layout: per-(h, s-tile) padded tile [64 d][72], contiguous 9216 B.
// ---------------------------------------------------------------------------
__global__ __launch_bounds__(256) void pack_all(const bf16* __restrict__ qkv,
                                                const int* __restrict__ pos,
                                                const float* __restrict__ bxg,
                                                const float* __restrict__ byg,
                                                const float* __restrict__ bzg,
                                                bf16* __restrict__ Qa,
                                                bf16* __restrict__ Ka,
                                                bf16* __restrict__ Vt) {
  const int st = blockIdx.x, h = blockIdx.y;
  const int t = threadIdx.x;
  __shared__ float bxs[61], bys[61], bzs[17];
  __shared__ float vtile[64][68];

  if (t < 61) { bxs[t] = bxg[t * NH + h]; bys[t] = byg[t * NH + h]; }
  if (t < 17) bzs[t] = bzg[t * NH + h];

  for (int i = t; i < 1024; i += 256) {
    int row = i >> 4, c4 = (i & 15) * 4;
    int sg = min(st * 64 + row, S_LEN - 1);
    bf16x4 v = *(const bf16x4*)&qkv[(size_t)sg * QKV_STRIDE + 2 * DM + h * HDIM + c4];
    *(float4*)&vtile[row][c4] = make_float4((float)v[0], (float)v[1], (float)v[2], (float)v[3]);
  }
  __syncthreads();

  for (int i = t; i < 2048; i += 256) {
    const int sl = i >> 5, sub = i & 31;
    const int s = st * 64 + sl;
    const int sc = min(s, S_LEN - 1);
    const int px = pos[sc * 3 + 0], py = pos[sc * 3 + 1], pz = pos[sc * 3 + 2];
    int j, P, pp;
    if (sub < 10)      { j = sub;      P = 10; pp = min(max(px, 0), 31); }
    else if (sub < 20) { j = sub - 10; P = 10; pp = min(max(py, 0), 31); }
    else               { j = sub - 20; P = 12; pp = min(max(pz, 0), 7);  }
    const float inv = __expf(-(float)j / (float)P * 9.210340371976184f);
    const float ang = (float)pp * inv;
    float sn, cs;
    __sincosf(ang, &sn, &cs);
    const size_t base = (size_t)sc * QKV_STRIDE + h * HDIM + 2 * sub;
    bf16x2 q2 = *(const bf16x2*)&qkv[base];
    bf16x2 k2 = *(const bf16x2*)&qkv[base + DM];
    float q0 = (float)q2[0], q1 = (float)q2[1];
    float k0 = (float)k2[0], k1 = (float)k2[1];
    const size_t qb = ((size_t)h * S_PAD + s) * AUGD;
    const size_t kb = ((size_t)h * S_PAD + s) * KA_STR;
    bf16x2 oq, ok;
    oq[0] = (bf16)((q0 * cs - q1 * sn) * 0.125f);
    oq[1] = (bf16)((q1 * cs + q0 * sn) * 0.125f);
    ok[0] = (bf16)(k0 * cs - k1 * sn);
    ok[1] = (bf16)(k1 * cs + k0 * sn);
    *(bf16x2*)&Qa[qb + 2 * sub] = oq;
    *(bf16x2*)&Ka[kb + 2 * sub] = ok;

    const int ix = min(max(px - sub, -30), 30) + 30;
    const int iy = min(max(py - sub, -30), 30) + 30;
    const int iz = min(max(pz - sub, -8), 8) + 8;
    Qa[qb + 64 + sub]  = (bf16)bxs[ix];
    Qa[qb + 96 + sub]  = (bf16)bys[iy];
    Qa[qb + 128 + sub] = (bf16)bzs[iz];
    Ka[kb + 64 + sub]  = (bf16)(sub == px ? 1.0f : 0.0f);
    Ka[kb + 96 + sub]  = (bf16)(sub == py ? 1.0f : 0.0f);
    Ka[kb + 128 + sub] = (bf16)(sub == pz ? 1.0f : 0.0f);
  }

  // V tile-transpose out: tile base contiguous, rows padded to 72
  bf16* vout = Vt + (size_t)(h * NT64 + st) * VT_TILE;
  for (int i = t; i < 1024; i += 256) {
    int d = i >> 4, s4 = (i & 15) * 4;
    bf16x4 o;
    o[0] = (bf16)vtile[s4 + 0][d];
    o[1] = (bf16)vtile[s4 + 1][d];
    o[2] = (bf16)vtile[s4 + 2][d];
    o[3] = (bf16)vtile[s4 + 3][d];
    *(bf16x4*)&vout[d * 72 + s4] = o;
  }
}

// ---------------------------------------------------------------------------
// Persistent split-K MFMA attention with FUSED combine. Grid = 1024 blocks
// (4/CU), XCD-pinned heads (h = b & 15) -> partials are XCD-L2-local. The
// last-arriving chunk block per (h,qt) (device atomic counter) performs the
// combine inline -- no separate kernel, and short-chain combines overlap
// long-chain compute. S^T formulation: P never touches LDS.
// ---------------------------------------------------------------------------
__global__ __launch_bounds__(256, 4) void attn_split(const bf16* __restrict__ Qa,
                                                     const bf16* __restrict__ Ka,
                                                     const bf16* __restrict__ Vt,
                                                     bf16* __restrict__ outb,
                                                     bf16* __restrict__ Opart,
                                                     float* __restrict__ lpart,
                                                     int* __restrict__ Ocnt) {
  const int b = blockIdx.x;
  const int h = b & 15;            // XCD pin: b%8 == h%8
  const int id = 63 - (b >> 4);
  int qt = 14;
  while (QT_BASE[qt] > id) --qt;
  const int c = id - QT_BASE[qt];
  const int chain = 2 * qt + 2;
  const int k0 = c * CHUNK;
  const int kend = min(k0 + CHUNK, chain);

  const int t = threadIdx.x, w = t >> 6, l = t & 63;
  const int quad = l >> 4, l16 = l & 15;

  __shared__ bf16 Ks[64][KA_STR];  // 64 keys x 160(+8 pad) aug dims
  __shared__ bf16 Vs[64][72];      // [dim][key], same flat layout as Vt tile
  __shared__ int lastflag;

  // Q fragments (B-operand of S^T = K.Q^T)
  bf16x8 bq[2][5];
  int igm[2];
#pragma unroll
  for (int mi = 0; mi < 2; ++mi) {
    const int qrow = qt * 128 + w * 32 + mi * 16 + l16;
    igm[mi] = qrow;
    const bf16* qp = &Qa[((size_t)h * S_PAD + qrow) * AUGD + quad * 8];
#pragma unroll
    for (int sg = 0; sg < 5; ++sg) bq[mi][sg] = *(const bf16x8*)(qp + sg * 32);
  }

  f32x4 O[2][4];   // O^T: row = d (quad*4+r within di*16), col = qrow (l16)
#pragma unroll
  for (int mi = 0; mi < 2; ++mi)
#pragma unroll
    for (int di = 0; di < 4; ++di) O[mi][di] = 0;
  float lacc[2] = {0.f, 0.f};

  bf16* KsF = &Ks[0][0];
  bf16* VsF = &Vs[0][0];

  for (int kt = k0; kt < kend; ++kt) {
    __syncthreads();
    // 30 DMA segments (21 K + 9 V), up to 8 per wave
    {
      const bf16* gk = &Ka[((size_t)h * S_PAD + kt * 64) * KA_STR];
      const bf16* gv = &Vt[(size_t)(h * NT64 + kt) * VT_TILE];
#pragma unroll
      for (int it = 0; it < 8; ++it) {
        const int sidx = w + it * 4;
        if (sidx < 21)      dma16(gk + sidx * 512 + l * 8, KsF + sidx * 512);
        else if (sidx < 30) dma16(gv + (sidx - 21) * 512 + l * 8, VsF + (sidx - 21) * 512);
      }
    }
    __syncthreads();

    // ---- S^T = K Q^T (includes bias); C: col=qrow(l16), row=key(quad*4+r)
    f32x4 sf[2][4];
#pragma unroll
    for (int ni = 0; ni < 4; ++ni) {
      bf16x8 ak[5];
      const bf16* kp = &Ks[ni * 16 + l16][quad * 8];
#pragma unroll
      for (int sg = 0; sg < 5; ++sg) ak[sg] = *(const bf16x8*)(kp + sg * 32);
#pragma unroll
      for (int mi = 0; mi < 2; ++mi) {
        f32x4 z = {0.f, 0.f, 0.f, 0.f};
#pragma unroll
        for (int sg = 0; sg < 5; ++sg) z = MFMA_BF16(ak[sg], bq[mi][sg], z, 0, 0, 0);
        sf[mi][ni] = z;
      }
    }

    // ---- exp + causal mask, packed directly into PV B-fragments ----
    short4v pf[2][4];
#pragma unroll
    for (int mi = 0; mi < 2; ++mi)
#pragma unroll
      for (int ni = 0; ni < 4; ++ni) {
        bf16x4 pb;
#pragma unroll
        for (int r = 0; r < 4; ++r) {
          const int key = kt * 64 + ni * 16 + quad * 4 + r;
          float p = __expf(sf[mi][ni][r]);
          if (key > igm[mi]) p = 0.f;
          lacc[mi] += p;
          pb[r] = (bf16)p;
        }
        pf[mi][ni] = as_s4(pb);
      }

    // ---- O^T += V^T P^T  (16x16x16 MFMA; A=V frag, B=P frag, regs only)
#pragma unroll
    for (int g = 0; g < 4; ++g)
#pragma unroll
      for (int di = 0; di < 4; ++di) {
        short4v vf = as_s4(*(const bf16x4*)&Vs[di * 16 + l16][g * 16 + quad * 4]);
#pragma unroll
        for (int mi = 0; mi < 2; ++mi)
          O[mi][di] = MFMA_BF16_K16(vf, pf[mi][g], O[mi][di], 0, 0, 0);
      }
  }

  // l: sum across the 4 quads holding the same qrow
#pragma unroll
  for (int mi = 0; mi < 2; ++mi) {
    float v = lacc[mi];
    v += __shfl_xor(v, 16);
    v += __shfl_xor(v, 32);
    lacc[mi] = v;
  }

  if (k0 == 0 && kend == chain) {
    // single chunk (qt <= 1): finalize directly
#pragma unroll
    for (int mi = 0; mi < 2; ++mi) {
      const int qrow = igm[mi];
      if (qrow < S_LEN) {
        const float inv = 1.0f / lacc[mi];
#pragma unroll
        for (int di = 0; di < 4; ++di) {
          bf16x4 o;
#pragma unroll
          for (int r = 0; r < 4; ++r) o[r] = (bf16)(O[mi][di][r] * inv);
          *(bf16x4*)&outb[(size_t)qrow * DM + h * HDIM + di * 16 + quad * 4] = o;
        }
      }
    }
  } else {
    // multi-chunk: write partial, then last-arriver combines
    const int cidx = h * NQMULTI + (qt - 2);
    bf16* ob = Opart + (size_t)cidx * MAXC * 8192 + (size_t)c * 8192;
#pragma unroll
    for (int mi = 0; mi < 2; ++mi) {
      const int row32 = w * 32 + mi * 16 + l16;
#pragma unroll
      for (int di = 0; di < 4; ++di) {
        bf16x4 o;
#pragma unroll
        for (int r = 0; r < 4; ++r) o[r] = (bf16)O[mi][di][r];
        *(bf16x4*)&ob[row32 * 64 + di * 16 + quad * 4] = o;
      }
    }
    if (quad == 0) {
      float* lb = lpart + (size_t)cidx * MAXC * 128 + (size_t)c * 128;
#pragma unroll
      for (int mi = 0; mi < 2; ++mi) lb[w * 32 + mi * 16 + l16] = lacc[mi];
    }
    __threadfence();
    const int nchunk = (chain + CHUNK - 1) / CHUNK;
    if (t == 0) {
      int prev = atomicAdd(&Ocnt[cidx], 1);
      lastflag = (prev == nchunk - 1) ? 1 : 0;
    }
    __syncthreads();
    if (lastflag) {
      __threadfence();  // acquire: see all chunks' partials
      const int row = t >> 1, half = t & 1;
      float acc[32];
#pragma unroll
      for (int j = 0; j < 32; ++j) acc[j] = 0.f;
      float lsum = 0.f;
      const bf16* pbase = Opart + (size_t)cidx * MAXC * 8192;
      const float* lbase = lpart + (size_t)cidx * MAXC * 128;
      for (int cc = 0; cc < nchunk; ++cc) {
        const bf16x8* p8 = (const bf16x8*)(pbase + cc * 8192 + row * 64 + half * 32);
#pragma unroll
        for (int j = 0; j < 4; ++j) {
          bf16x8 v = p8[j];
#pragma unroll
          for (int e = 0; e < 8; ++e) acc[j * 8 + e] += (float)v[e];
        }
        lsum += lbase[cc * 128 + row];
      }
      const int s = qt * 128 + row;
      if (s < S_LEN) {
        const float inv = 1.0f / lsum;
        bf16* op = outb + (size_t)s * DM + h * HDIM + half * 32;
#pragma unroll
        for (int j = 0; j < 8; ++j) {
          bf16x4 o;
          o[0] = (bf16)(acc[j * 4 + 0] * inv);
          o[1] = (bf16)(acc[j * 4 + 1] * inv);
          o[2] = (bf16)(acc[j * 4 + 2] * inv);
          o[3] = (bf16)(acc[j * 4 + 3] * inv);
          *(bf16x4*)&op[j * 4] = o;
        }
      }
    }
  }
}

// ---------------------------------------------------------------------------
extern "C" void kernel_launch(void* const* d_in, const int* in_sizes, int n_in,
                              void* d_out, int out_size, void* d_ws, size_t ws_size,
                              hipStream_t stream) {
  const float* x    = (const float*)d_in[0];
  const float* Wqkv = (const float*)d_in[1];
  const float* Wout = (const float*)d_in[2];
  const float* bx   = (const float*)d_in[3];
  const float* by   = (const float*)d_in[4];
  const float* bz   = (const float*)d_in[5];
  const int*   pos  = (const int*)d_in[6];
  float* out = (float*)d_out;

  // Workspace overlay: Opart (27.3 MB bf16) reuses xb/wqkvb/qkvb (21.5 MB,
  // all dead by the time attn_split runs).
  char* ws = (char*)d_ws;
  bf16* Opart = (bf16*)ws;
  bf16* xb    = (bf16*)ws;
  bf16* wqkvb = xb + (size_t)S_LEN * DM;
  bf16* qkvb  = wqkvb + (size_t)QKV_STRIDE * DM;
  ws += (size_t)NH * NQMULTI * MAXC * 8192 * 2;
  bf16* woutb = (bf16*)ws;   ws += (size_t)DM * DM * 2;
  bf16* Qaug  = (bf16*)ws;   ws += (size_t)NH * S_PAD * AUGD * 2;
  bf16* Kaug  = (bf16*)ws;   ws += (size_t)NH * S_PAD * KA_STR * 2;
  bf16* Vtb   = (bf16*)ws;   ws += (size_t)NH * NT64 * VT_TILE * 2;
  bf16* attnb = (bf16*)ws;   ws += (size_t)S_LEN * DM * 2;
  float* lpart = (float*)ws; ws += (size_t)NH * NQMULTI * MAXC * 128 * 4;
  int* Ocnt = (int*)ws;      ws += NCNT * 4;

  const int na4 = S_LEN * DM / 4, nb4 = QKV_STRIDE * DM / 4, nc4 = DM * DM / 4;
  const int ntot = na4 + nb4 + nc4;
  cvt3<<<dim3((ntot + 255) / 256), 256, 0, stream>>>(x, xb, na4, Wqkv, wqkvb, nb4,
                                                     Wout, woutb, nc4, Ocnt);
  gemm_bt<bf16><<<dim3(QKV_STRIDE / 64, NQT128), 256, 0, stream>>>(
      xb, wqkvb, qkvb, S_LEN, QKV_STRIDE, DM);
  pack_all<<<dim3(NT64, NH), 256, 0, stream>>>(qkvb, pos, bx, by, bz, Qaug, Kaug, Vtb);
  attn_split<<<dim3(NH * NCHUNK_HEAD), 256, 0, stream>>>(Qaug, Kaug, Vtb, attnb,
                                                         Opart, lpart, Ocnt);
  gemm_bt64<<<dim3(DM / 64, (S_LEN + 63) / 64), 256, 0, stream>>>(
      attnb, woutb, out, S_LEN, DM, DM);
}

// Round 11
// 325.743 us; speedup vs baseline: 1.2944x; 1.2944x over previous
//
#include <hip/hip_runtime.h>

typedef __bf16 bf16;
typedef __bf16 bf16x2 __attribute__((ext_vector_type(2)));
typedef __bf16 bf16x4 __attribute__((ext_vector_type(4)));
typedef __bf16 bf16x8 __attribute__((ext_vector_type(8)));
typedef float  f32x4  __attribute__((ext_vector_type(4)));
typedef short  short4v __attribute__((ext_vector_type(4)));

#define S_LEN 1863
#define S_PAD 1920
#define DM 1024
#define NH 16
#define HDIM 64
#define AUGD 160      // 64 qk dims + 32 x-onehot + 32 y-onehot + 32 z-onehot
#define KA_STR 168    // Kaug row stride (336 B): DMA-contiguous AND 2-way-bank-free
#define VT_TILE 4608  // V tile: 64 d-rows x 72 (pad) = 9216 B, 9 DMA segs
#define QKV_STRIDE 3072
#define NQT128 15
#define NT64 30       // 64-row s-tiles
#define CHUNK 4
#define MAXC 8
#define NQMULTI 13    // q-tiles with >1 chunk (qt = 2..14)
#define NCHUNK_HEAD 64
#define NCNT (NH * NQMULTI)

#define MFMA_BF16 __builtin_amdgcn_mfma_f32_16x16x32_bf16
#define MFMA_BF16_K16 __builtin_amdgcn_mfma_f32_16x16x16bf16_1k

__constant__ int QT_BASE[15] = {0, 1, 2, 4, 6, 9, 12, 16, 20, 25, 30, 36, 42, 49, 56};

// async global->LDS copy, 16 B per lane; lds dest = uniform base + lane*16
__device__ __forceinline__ void dma16(const bf16* g, bf16* l) {
  __builtin_amdgcn_global_load_lds(
      (const __attribute__((address_space(1))) unsigned int*)g,
      (__attribute__((address_space(3))) unsigned int*)l, 16, 0, 0);
}

__device__ __forceinline__ short4v as_s4(bf16x4 v) {
  return __builtin_bit_cast(short4v, v);
}

// ---------------------------------------------------------------------------
// fused fp32->bf16 conversion of x, Wqkv, Wout + zeroing of combine counters
// ---------------------------------------------------------------------------
__global__ void cvt3(const float* __restrict__ a, bf16* __restrict__ oa, int na4,
                     const float* __restrict__ b, bf16* __restrict__ ob, int nb4,
                     const float* __restrict__ c, bf16* __restrict__ oc, int nc4,
                     int* __restrict__ Ocnt) {
  if (blockIdx.x == 0 && threadIdx.x < NCNT) Ocnt[threadIdx.x] = 0;
  int j = blockIdx.x * blockDim.x + threadIdx.x;
  const float* s; bf16* d;
  if (j < na4) { s = a; d = oa; }
  else {
    j -= na4;
    if (j < nb4) { s = b; d = ob; }
    else { j -= nb4; if (j >= nc4) return; s = c; d = oc; }
  }
  float4 v = ((const float4*)s)[j];
  bf16x4 o;
  o[0] = (bf16)v.x; o[1] = (bf16)v.y; o[2] = (bf16)v.z; o[3] = (bf16)v.w;
  ((bf16x4*)d)[j] = o;
}

// ---------------------------------------------------------------------------
// bf16 MFMA GEMM, 128x64 tile, BK=32, 4 waves, global_load_lds staging.
// (R8-proven config: 720 blocks for gemm1.)
// ---------------------------------------------------------------------------
template <typename T>
__global__ __launch_bounds__(256) void gemm_bt(const bf16* __restrict__ A,
                                               const bf16* __restrict__ B,
                                               T* __restrict__ C,
                                               int M, int N, int K) {
  __shared__ bf16 As[128][32];
  __shared__ bf16 Bs[64][32];
  const int t = threadIdx.x;
  const int w = t >> 6, l = t & 63;
  const int quad = l >> 4, l16 = l & 15;
  const int wm = w >> 1, wn = w & 1;
  const int bm = blockIdx.y * 128, bn = blockIdx.x * 64;
  const int lr = l >> 2;          // 0..15 row within a 16-row DMA segment
  const int lc = (l & 3) * 8;     // col element offset (16 B per lane)

  f32x4 acc[4][2];
#pragma unroll
  for (int mi = 0; mi < 4; ++mi)
#pragma unroll
    for (int ni = 0; ni < 2; ++ni) acc[mi][ni] = 0;

  for (int k0 = 0; k0 < K; k0 += 32) {
    __syncthreads();
#pragma unroll
    for (int p = 0; p < 2; ++p) {
      const int seg = 2 * w + p;
      dma16(&A[(size_t)min(bm + seg * 16 + lr, M - 1) * K + k0 + lc], &As[seg * 16][0]);
    }
    dma16(&B[(size_t)(bn + w * 16 + lr) * K + k0 + lc], &Bs[w * 16][0]);
    __syncthreads();

    bf16x8 af[4], bfr[2];
#pragma unroll
    for (int mi = 0; mi < 4; ++mi) af[mi]  = *(bf16x8*)&As[wm * 64 + mi * 16 + l16][quad * 8];
#pragma unroll
    for (int ni = 0; ni < 2; ++ni) bfr[ni] = *(bf16x8*)&Bs[wn * 32 + ni * 16 + l16][quad * 8];
#pragma unroll
    for (int mi = 0; mi < 4; ++mi)
#pragma unroll
      for (int ni = 0; ni < 2; ++ni)
        acc[mi][ni] = MFMA_BF16(af[mi], bfr[ni], acc[mi][ni], 0, 0, 0);
  }

#pragma unroll
  for (int mi = 0; mi < 4; ++mi)
#pragma unroll
    for (int r = 0; r < 4; ++r) {
      int m = bm + wm * 64 + mi * 16 + quad * 4 + r;
      if (m < M) {
#pragma unroll
        for (int ni = 0; ni < 2; ++ni)
          C[(size_t)m * N + bn + wn * 32 + ni * 16 + l16] = (T)acc[mi][ni][r];
      }
    }
}

// ---------------------------------------------------------------------------
// bf16 MFMA GEMM, 64x64 tile with DMA staging (N=1024 proj; 480 blocks).
// ---------------------------------------------------------------------------
__global__ __launch_bounds__(256) void gemm_bt64(const bf16* __restrict__ A,
                                                 const bf16* __restrict__ B,
                                                 float* __restrict__ C,
                                                 int M, int N, int K) {
  __shared__ bf16 As[64][32];
  __shared__ bf16 Bs[64][32];
  const int t = threadIdx.x;
  const int w = t >> 6, l = t & 63;
  const int quad = l >> 4, l16 = l & 15;
  const int wm = w >> 1, wn = w & 1;
  const int bm = blockIdx.y * 64, bn = blockIdx.x * 64;
  const int lr = l >> 2;
  const int lc = (l & 3) * 8;

  f32x4 acc[2][2];
#pragma unroll
  for (int mi = 0; mi < 2; ++mi)
#pragma unroll
    for (int ni = 0; ni < 2; ++ni) acc[mi][ni] = 0;

  for (int k0 = 0; k0 < K; k0 += 32) {
    __syncthreads();
    dma16(&A[(size_t)min(bm + w * 16 + lr, M - 1) * K + k0 + lc], &As[w * 16][0]);
    dma16(&B[(size_t)(bn + w * 16 + lr) * K + k0 + lc], &Bs[w * 16][0]);
    __syncthreads();

    bf16x8 af[2], bfr[2];
#pragma unroll
    for (int mi = 0; mi < 2; ++mi) af[mi]  = *(bf16x8*)&As[wm * 32 + mi * 16 + l16][quad * 8];
#pragma unroll
    for (int ni = 0; ni < 2; ++ni) bfr[ni] = *(bf16x8*)&Bs[wn * 32 + ni * 16 + l16][quad * 8];
#pragma unroll
    for (int mi = 0; mi < 2; ++mi)
#pragma unroll
      for (int ni = 0; ni < 2; ++ni)
        acc[mi][ni] = MFMA_BF16(af[mi], bfr[ni], acc[mi][ni], 0, 0, 0);
  }

#pragma unroll
  for (int mi = 0; mi < 2; ++mi)
#pragma unroll
    for (int r = 0; r < 4; ++r) {
      int m = bm + wm * 32 + mi * 16 + quad * 4 + r;
      if (m < M) {
#pragma unroll
        for (int ni = 0; ni < 2; ++ni)
          C[(size_t)m * N + bn + wn * 32 + ni * 16 + l16] = acc[mi][ni][r];
      }
    }
}

// ---------------------------------------------------------------------------
// Fused pack: RoPE + bias-augmented Q/K build + V tile-transpose.
// Vt layout: per-(h, s-tile) padded tile [64 d][72], contiguous 9216 B.
// ---------------------------------------------------------------------------
__global__ __launch_bounds__(256) void pack_all(const bf16* __restrict__ qkv,
                                                const int* __restrict__ pos,
                                                const float* __restrict__ bxg,
                                                const float* __restrict__ byg,
                                                const float* __restrict__ bzg,
                                                bf16* __restrict__ Qa,
                                                bf16* __restrict__ Ka,
                                                bf16* __restrict__ Vt) {
  const int st = blockIdx.x, h = blockIdx.y;
  const int t = threadIdx.x;
  __shared__ float bxs[61], bys[61], bzs[17];
  __shared__ float vtile[64][68];

  if (t < 61) { bxs[t] = bxg[t * NH + h]; bys[t] = byg[t * NH + h]; }
  if (t < 17) bzs[t] = bzg[t * NH + h];

  for (int i = t; i < 1024; i += 256) {
    int row = i >> 4, c4 = (i & 15) * 4;
    int sg = min(st * 64 + row, S_LEN - 1);
    bf16x4 v = *(const bf16x4*)&qkv[(size_t)sg * QKV_STRIDE + 2 * DM + h * HDIM + c4];
    *(float4*)&vtile[row][c4] = make_float4((float)v[0], (float)v[1], (float)v[2], (float)v[3]);
  }
  __syncthreads();

  for (int i = t; i < 2048; i += 256) {
    const int sl = i >> 5, sub = i & 31;
    const int s = st * 64 + sl;
    const int sc = min(s, S_LEN - 1);
    const int px = pos[sc * 3 + 0], py = pos[sc * 3 + 1], pz = pos[sc * 3 + 2];
    int j, P, pp;
    if (sub < 10)      { j = sub;      P = 10; pp = min(max(px, 0), 31); }
    else if (sub < 20) { j = sub - 10; P = 10; pp = min(max(py, 0), 31); }
    else               { j = sub - 20; P = 12; pp = min(max(pz, 0), 7);  }
    const float inv = __expf(-(float)j / (float)P * 9.210340371976184f);
    const float ang = (float)pp * inv;
    float sn, cs;
    __sincosf(ang, &sn, &cs);
    const size_t base = (size_t)sc * QKV_STRIDE + h * HDIM + 2 * sub;
    bf16x2 q2 = *(const bf16x2*)&qkv[base];
    bf16x2 k2 = *(const bf16x2*)&qkv[base + DM];
    float q0 = (float)q2[0], q1 = (float)q2[1];
    float k0 = (float)k2[0], k1 = (float)k2[1];
    const size_t qb = ((size_t)h * S_PAD + s) * AUGD;
    const size_t kb = ((size_t)h * S_PAD + s) * KA_STR;
    bf16x2 oq, ok;
    oq[0] = (bf16)((q0 * cs - q1 * sn) * 0.125f);
    oq[1] = (bf16)((q1 * cs + q0 * sn) * 0.125f);
    ok[0] = (bf16)(k0 * cs - k1 * sn);
    ok[1] = (bf16)(k1 * cs + k0 * sn);
    *(bf16x2*)&Qa[qb + 2 * sub] = oq;
    *(bf16x2*)&Ka[kb + 2 * sub] = ok;

    const int ix = min(max(px - sub, -30), 30) + 30;
    const int iy = min(max(py - sub, -30), 30) + 30;
    const int iz = min(max(pz - sub, -8), 8) + 8;
    Qa[qb + 64 + sub]  = (bf16)bxs[ix];
    Qa[qb + 96 + sub]  = (bf16)bys[iy];
    Qa[qb + 128 + sub] = (bf16)bzs[iz];
    Ka[kb + 64 + sub]  = (bf16)(sub == px ? 1.0f : 0.0f);
    Ka[kb + 96 + sub]  = (bf16)(sub == py ? 1.0f : 0.0f);
    Ka[kb + 128 + sub] = (bf16)(sub == pz ? 1.0f : 0.0f);
  }

  // V tile-transpose out: tile base contiguous, rows padded to 72
  bf16* vout = Vt + (size_t)(h * NT64 + st) * VT_TILE;
  for (int i = t; i < 1024; i += 256) {
    int d = i >> 4, s4 = (i & 15) * 4;
    bf16x4 o;
    o[0] = (bf16)vtile[s4 + 0][d];
    o[1] = (bf16)vtile[s4 + 1][d];
    o[2] = (bf16)vtile[s4 + 2][d];
    o[3] = (bf16)vtile[s4 + 3][d];
    *(bf16x4*)&vout[d * 72 + s4] = o;
  }
}

// ---------------------------------------------------------------------------
// Persistent split-K MFMA attention with fused last-arriver combine.
// DEFAULT launch bounds -- R10's (256,4) cap forced 64 VGPRs and spilled
// ~350 MB to scratch (FETCH+WRITE counters); never cap below need.
// Grid = 1024 blocks (4/CU), XCD-pinned heads (h = b & 15). S^T formulation:
// P never touches LDS. All staging via global_load_lds (21 K + 9 V segs).
// ---------------------------------------------------------------------------
__global__ __launch_bounds__(256) void attn_split(const bf16* __restrict__ Qa,
                                                  const bf16* __restrict__ Ka,
                                                  const bf16* __restrict__ Vt,
                                                  bf16* __restrict__ outb,
                                                  bf16* __restrict__ Opart,
                                                  float* __restrict__ lpart,
                                                  int* __restrict__ Ocnt) {
  const int b = blockIdx.x;
  const int h = b & 15;            // XCD pin: b%8 == h%8
  const int id = 63 - (b >> 4);
  int qt = 14;
  while (QT_BASE[qt] > id) --qt;
  const int c = id - QT_BASE[qt];
  const int chain = 2 * qt + 2;
  const int k0 = c * CHUNK;
  const int kend = min(k0 + CHUNK, chain);

  const int t = threadIdx.x, w = t >> 6, l = t & 63;
  const int quad = l >> 4, l16 = l & 15;

  __shared__ bf16 Ks[64][KA_STR];  // 64 keys x 160(+8 pad) aug dims
  __shared__ bf16 Vs[64][72];      // [dim][key], same flat layout as Vt tile
  __shared__ int lastflag;

  // Q fragments (B-operand of S^T = K.Q^T)
  bf16x8 bq[2][5];
  int igm[2];
#pragma unroll
  for (int mi = 0; mi < 2; ++mi) {
    const int qrow = qt * 128 + w * 32 + mi * 16 + l16;
    igm[mi] = qrow;
    const bf16* qp = &Qa[((size_t)h * S_PAD + qrow) * AUGD + quad * 8];
#pragma unroll
    for (int sg = 0; sg < 5; ++sg) bq[mi][sg] = *(const bf16x8*)(qp + sg * 32);
  }

  f32x4 O[2][4];   // O^T: row = d (quad*4+r within di*16), col = qrow (l16)
#pragma unroll
  for (int mi = 0; mi < 2; ++mi)
#pragma unroll
    for (int di = 0; di < 4; ++di) O[mi][di] = 0;
  float lacc[2] = {0.f, 0.f};

  bf16* KsF = &Ks[0][0];
  bf16* VsF = &Vs[0][0];

  for (int kt = k0; kt < kend; ++kt) {
    __syncthreads();
    // 30 DMA segments (21 K + 9 V), up to 8 per wave
    {
      const bf16* gk = &Ka[((size_t)h * S_PAD + kt * 64) * KA_STR];
      const bf16* gv = &Vt[(size_t)(h * NT64 + kt) * VT_TILE];
#pragma unroll
      for (int it = 0; it < 8; ++it) {
        const int sidx = w + it * 4;
        if (sidx < 21)      dma16(gk + sidx * 512 + l * 8, KsF + sidx * 512);
        else if (sidx < 30) dma16(gv + (sidx - 21) * 512 + l * 8, VsF + (sidx - 21) * 512);
      }
    }
    __syncthreads();

    // ---- S^T = K Q^T (includes bias); C: col=qrow(l16), row=key(quad*4+r)
    f32x4 sf[2][4];
#pragma unroll
    for (int ni = 0; ni < 4; ++ni) {
      bf16x8 ak[5];
      const bf16* kp = &Ks[ni * 16 + l16][quad * 8];
#pragma unroll
      for (int sg = 0; sg < 5; ++sg) ak[sg] = *(const bf16x8*)(kp + sg * 32);
#pragma unroll
      for (int mi = 0; mi < 2; ++mi) {
        f32x4 z = {0.f, 0.f, 0.f, 0.f};
#pragma unroll
        for (int sg = 0; sg < 5; ++sg) z = MFMA_BF16(ak[sg], bq[mi][sg], z, 0, 0, 0);
        sf[mi][ni] = z;
      }
    }

    // ---- exp + causal mask, packed directly into PV B-fragments ----
    short4v pf[2][4];
#pragma unroll
    for (int mi = 0; mi < 2; ++mi)
#pragma unroll
      for (int ni = 0; ni < 4; ++ni) {
        bf16x4 pb;
#pragma unroll
        for (int r = 0; r < 4; ++r) {
          const int key = kt * 64 + ni * 16 + quad * 4 + r;
          float p = __expf(sf[mi][ni][r]);
          if (key > igm[mi]) p = 0.f;
          lacc[mi] += p;
          pb[r] = (bf16)p;
        }
        pf[mi][ni] = as_s4(pb);
      }

    // ---- O^T += V^T P^T  (16x16x16 MFMA; A=V frag, B=P frag, regs only)
#pragma unroll
    for (int g = 0; g < 4; ++g)
#pragma unroll
      for (int di = 0; di < 4; ++di) {
        short4v vf = as_s4(*(const bf16x4*)&Vs[di * 16 + l16][g * 16 + quad * 4]);
#pragma unroll
        for (int mi = 0; mi < 2; ++mi)
          O[mi][di] = MFMA_BF16_K16(vf, pf[mi][g], O[mi][di], 0, 0, 0);
      }
  }

  // l: sum across the 4 quads holding the same qrow
#pragma unroll
  for (int mi = 0; mi < 2; ++mi) {
    float v = lacc[mi];
    v += __shfl_xor(v, 16);
    v += __shfl_xor(v, 32);
    lacc[mi] = v;
  }

  if (k0 == 0 && kend == chain) {
    // single chunk (qt <= 1): finalize directly
#pragma unroll
    for (int mi = 0; mi < 2; ++mi) {
      const int qrow = igm[mi];
      if (qrow < S_LEN) {
        const float inv = 1.0f / lacc[mi];
#pragma unroll
        for (int di = 0; di < 4; ++di) {
          bf16x4 o;
#pragma unroll
          for (int r = 0; r < 4; ++r) o[r] = (bf16)(O[mi][di][r] * inv);
          *(bf16x4*)&outb[(size_t)qrow * DM + h * HDIM + di * 16 + quad * 4] = o;
        }
      }
    }
  } else {
    // multi-chunk: write partial; last arriver combines inline
    const int cidx = h * NQMULTI + (qt - 2);
    bf16* ob = Opart + (size_t)cidx * MAXC * 8192 + (size_t)c * 8192;
#pragma unroll
    for (int mi = 0; mi < 2; ++mi) {
      const int row32 = w * 32 + mi * 16 + l16;
#pragma unroll
      for (int di = 0; di < 4; ++di) {
        bf16x4 o;
#pragma unroll
        for (int r = 0; r < 4; ++r) o[r] = (bf16)O[mi][di][r];
        *(bf16x4*)&ob[row32 * 64 + di * 16 + quad * 4] = o;
      }
    }
    if (quad == 0) {
      float* lb = lpart + (size_t)cidx * MAXC * 128 + (size_t)c * 128;
#pragma unroll
      for (int mi = 0; mi < 2; ++mi) lb[w * 32 + mi * 16 + l16] = lacc[mi];
    }
    __threadfence();
    const int nchunk = (chain + CHUNK - 1) / CHUNK;
    if (t == 0) {
      int prev = atomicAdd(&Ocnt[cidx], 1);
      lastflag = (prev == nchunk - 1) ? 1 : 0;
    }
    __syncthreads();
    if (lastflag) {
      __threadfence();
      const int row = t >> 1, half = t & 1;
      float acc[32];
#pragma unroll
      for (int j = 0; j < 32; ++j) acc[j] = 0.f;
      float lsum = 0.f;
      const bf16* pbase = Opart + (size_t)cidx * MAXC * 8192;
      const float* lbase = lpart + (size_t)cidx * MAXC * 128;
      for (int cc = 0; cc < nchunk; ++cc) {
        const bf16x8* p8 = (const bf16x8*)(pbase + cc * 8192 + row * 64 + half * 32);
#pragma unroll
        for (int j = 0; j < 4; ++j) {
          bf16x8 v = p8[j];
#pragma unroll
          for (int e = 0; e < 8; ++e) acc[j * 8 + e] += (float)v[e];
        }
        lsum += lbase[cc * 128 + row];
      }
      const int s = qt * 128 + row;
      if (s < S_LEN) {
        const float inv = 1.0f / lsum;
        bf16* op = outb + (size_t)s * DM + h * HDIM + half * 32;
#pragma unroll
        for (int j = 0; j < 8; ++j) {
          bf16x4 o;
          o[0] = (bf16)(acc[j * 4 + 0] * inv);
          o[1] = (bf16)(acc[j * 4 + 1] * inv);
          o[2] = (bf16)(acc[j * 4 + 2] * inv);
          o[3] = (bf16)(acc[j * 4 + 3] * inv);
          *(bf16x4*)&op[j * 4] = o;
        }
      }
    }
  }
}

// ---------------------------------------------------------------------------
extern "C" void kernel_launch(void* const* d_in, const int* in_sizes, int n_in,
                              void* d_out, int out_size, void* d_ws, size_t ws_size,
                              hipStream_t stream) {
  const float* x    = (const float*)d_in[0];
  const float* Wqkv = (const float*)d_in[1];
  const float* Wout = (const float*)d_in[2];
  const float* bx   = (const float*)d_in[3];
  const float* by   = (const float*)d_in[4];
  const float* bz   = (const float*)d_in[5];
  const int*   pos  = (const int*)d_in[6];
  float* out = (float*)d_out;

  // Workspace overlay: Opart (27.3 MB bf16) reuses xb/wqkvb/qkvb (21.5 MB,
  // all dead by the time attn_split runs).
  char* ws = (char*)d_ws;
  bf16* Opart = (bf16*)ws;
  bf16* xb    = (bf16*)ws;
  bf16* wqkvb = xb + (size_t)S_LEN * DM;
  bf16* qkvb  = wqkvb + (size_t)QKV_STRIDE * DM;
  ws += (size_t)NH * NQMULTI * MAXC * 8192 * 2;
  bf16* woutb = (bf16*)ws;   ws += (size_t)DM * DM * 2;
  bf16* Qaug  = (bf16*)ws;   ws += (size_t)NH * S_PAD * AUGD * 2;
  bf16* Kaug  = (bf16*)ws;   ws += (size_t)NH * S_PAD * KA_STR * 2;
  bf16* Vtb   = (bf16*)ws;   ws += (size_t)NH * NT64 * VT_TILE * 2;
  bf16* attnb = (bf16*)ws;   ws += (size_t)S_LEN * DM * 2;
  float* lpart = (float*)ws; ws += (size_t)NH * NQMULTI * MAXC * 128 * 4;
  int* Ocnt = (int*)ws;      ws += NCNT * 4;

  const int na4 = S_LEN * DM / 4, nb4 = QKV_STRIDE * DM / 4, nc4 = DM * DM / 4;
  const int ntot = na4 + nb4 + nc4;
  cvt3<<<dim3((ntot + 255) / 256), 256, 0, stream>>>(x, xb, na4, Wqkv, wqkvb, nb4,
                                                     Wout, woutb, nc4, Ocnt);
  gemm_bt<bf16><<<dim3(QKV_STRIDE / 64, NQT128), 256, 0, stream>>>(
      xb, wqkvb, qkvb, S_LEN, QKV_STRIDE, DM);
  pack_all<<<dim3(NT64, NH), 256, 0, stream>>>(qkvb, pos, bx, by, bz, Qaug, Kaug, Vtb);
  attn_split<<<dim3(NH * NCHUNK_HEAD), 256, 0, stream>>>(Qaug, Kaug, Vtb, attnb,
                                                         Opart, lpart, Ocnt);
  gemm_bt64<<<dim3(DM / 64, (S_LEN + 63) / 64), 256, 0, stream>>>(
      attnb, woutb, out, S_LEN, DM, DM);
}

// Round 12
// 165.105 us; speedup vs baseline: 2.5537x; 1.9729x over previous
//
#include <hip/hip_runtime.h>

typedef __bf16 bf16;
typedef __bf16 bf16x2 __attribute__((ext_vector_type(2)));
typedef __bf16 bf16x4 __attribute__((ext_vector_type(4)));
typedef __bf16 bf16x8 __attribute__((ext_vector_type(8)));
typedef float  f32x4  __attribute__((ext_vector_type(4)));
typedef short  short4v __attribute__((ext_vector_type(4)));

#define S_LEN 1863
#define S_PAD 1920
#define DM 1024
#define NH 16
#define HDIM 64
#define AUGD 160      // 64 qk dims + 32 x-onehot + 32 y-onehot + 32 z-onehot
#define KA_STR 168    // Kaug row stride (336 B): DMA-contiguous AND 2-way-bank-free
#define QKV_STRIDE 3072
#define NQT128 15
#define CHUNK 4
#define MAXC 8
#define NQMULTI 13    // q-tiles with >1 chunk (qt = 2..14)
#define NCHUNK_HEAD 64

#define MFMA_BF16 __builtin_amdgcn_mfma_f32_16x16x32_bf16
#define MFMA_BF16_K16 __builtin_amdgcn_mfma_f32_16x16x16bf16_1k

__constant__ int QT_BASE[15] = {0, 1, 2, 4, 6, 9, 12, 16, 20, 25, 30, 36, 42, 49, 56};

// async global->LDS copy, 16 B per lane; lds dest = uniform base + lane*16
__device__ __forceinline__ void dma16(const bf16* g, bf16* l) {
  __builtin_amdgcn_global_load_lds(
      (const __attribute__((address_space(1))) unsigned int*)g,
      (__attribute__((address_space(3))) unsigned int*)l, 16, 0, 0);
}

__device__ __forceinline__ short4v as_s4(bf16x4 v) {
  return __builtin_bit_cast(short4v, v);
}

// ---------------------------------------------------------------------------
// fused fp32->bf16 conversion of x, Wqkv, Wout
// ---------------------------------------------------------------------------
__global__ void cvt3(const float* __restrict__ a, bf16* __restrict__ oa, int na4,
                     const float* __restrict__ b, bf16* __restrict__ ob, int nb4,
                     const float* __restrict__ c, bf16* __restrict__ oc, int nc4) {
  int j = blockIdx.x * blockDim.x + threadIdx.x;
  const float* s; bf16* d;
  if (j < na4) { s = a; d = oa; }
  else {
    j -= na4;
    if (j < nb4) { s = b; d = ob; }
    else { j -= nb4; if (j >= nc4) return; s = c; d = oc; }
  }
  float4 v = ((const float4*)s)[j];
  bf16x4 o;
  o[0] = (bf16)v.x; o[1] = (bf16)v.y; o[2] = (bf16)v.z; o[3] = (bf16)v.w;
  ((bf16x4*)d)[j] = o;
}

// ---------------------------------------------------------------------------
// bf16 MFMA GEMM, 128x64 tile, BK=32, 4 waves, global_load_lds staging.
// ---------------------------------------------------------------------------
template <typename T>
__global__ __launch_bounds__(256) void gemm_bt(const bf16* __restrict__ A,
                                               const bf16* __restrict__ B,
                                               T* __restrict__ C,
                                               int M, int N, int K) {
  __shared__ bf16 As[128][32];
  __shared__ bf16 Bs[64][32];
  const int t = threadIdx.x;
  const int w = t >> 6, l = t & 63;
  const int quad = l >> 4, l16 = l & 15;
  const int wm = w >> 1, wn = w & 1;
  const int bm = blockIdx.y * 128, bn = blockIdx.x * 64;
  const int lr = l >> 2;          // 0..15 row within a 16-row DMA segment
  const int lc = (l & 3) * 8;     // col element offset (16 B per lane)

  f32x4 acc[4][2];
#pragma unroll
  for (int mi = 0; mi < 4; ++mi)
#pragma unroll
    for (int ni = 0; ni < 2; ++ni) acc[mi][ni] = 0;

  for (int k0 = 0; k0 < K; k0 += 32) {
    __syncthreads();
    // A: 8 segments of 16 rows; wave w does segs 2w, 2w+1. B: 4 segs, one/wave.
#pragma unroll
    for (int p = 0; p < 2; ++p) {
      const int seg = 2 * w + p;
      dma16(&A[(size_t)min(bm + seg * 16 + lr, M - 1) * K + k0 + lc], &As[seg * 16][0]);
    }
    dma16(&B[(size_t)(bn + w * 16 + lr) * K + k0 + lc], &Bs[w * 16][0]);
    __syncthreads();

    bf16x8 af[4], bfr[2];
#pragma unroll
    for (int mi = 0; mi < 4; ++mi) af[mi]  = *(bf16x8*)&As[wm * 64 + mi * 16 + l16][quad * 8];
#pragma unroll
    for (int ni = 0; ni < 2; ++ni) bfr[ni] = *(bf16x8*)&Bs[wn * 32 + ni * 16 + l16][quad * 8];
#pragma unroll
    for (int mi = 0; mi < 4; ++mi)
#pragma unroll
      for (int ni = 0; ni < 2; ++ni)
        acc[mi][ni] = MFMA_BF16(af[mi], bfr[ni], acc[mi][ni], 0, 0, 0);
  }

#pragma unroll
  for (int mi = 0; mi < 4; ++mi)
#pragma unroll
    for (int r = 0; r < 4; ++r) {
      int m = bm + wm * 64 + mi * 16 + quad * 4 + r;
      if (m < M) {
#pragma unroll
        for (int ni = 0; ni < 2; ++ni)
          C[(size_t)m * N + bn + wn * 32 + ni * 16 + l16] = (T)acc[mi][ni][r];
      }
    }
}

// ---------------------------------------------------------------------------
// bf16 MFMA GEMM, 64x64 tile with DMA staging (N=1024 proj; 480 blocks).
// ---------------------------------------------------------------------------
__global__ __launch_bounds__(256) void gemm_bt64(const bf16* __restrict__ A,
                                                 const bf16* __restrict__ B,
                                                 float* __restrict__ C,
                                                 int M, int N, int K) {
  __shared__ bf16 As[64][32];
  __shared__ bf16 Bs[64][32];
  const int t = threadIdx.x;
  const int w = t >> 6, l = t & 63;
  const int quad = l >> 4, l16 = l & 15;
  const int wm = w >> 1, wn = w & 1;
  const int bm = blockIdx.y * 64, bn = blockIdx.x * 64;
  const int lr = l >> 2;
  const int lc = (l & 3) * 8;

  f32x4 acc[2][2];
#pragma unroll
  for (int mi = 0; mi < 2; ++mi)
#pragma unroll
    for (int ni = 0; ni < 2; ++ni) acc[mi][ni] = 0;

  for (int k0 = 0; k0 < K; k0 += 32) {
    __syncthreads();
    dma16(&A[(size_t)min(bm + w * 16 + lr, M - 1) * K + k0 + lc], &As[w * 16][0]);
    dma16(&B[(size_t)(bn + w * 16 + lr) * K + k0 + lc], &Bs[w * 16][0]);
    __syncthreads();

    bf16x8 af[2], bfr[2];
#pragma unroll
    for (int mi = 0; mi < 2; ++mi) af[mi]  = *(bf16x8*)&As[wm * 32 + mi * 16 + l16][quad * 8];
#pragma unroll
    for (int ni = 0; ni < 2; ++ni) bfr[ni] = *(bf16x8*)&Bs[wn * 32 + ni * 16 + l16][quad * 8];
#pragma unroll
    for (int mi = 0; mi < 2; ++mi)
#pragma unroll
      for (int ni = 0; ni < 2; ++ni)
        acc[mi][ni] = MFMA_BF16(af[mi], bfr[ni], acc[mi][ni], 0, 0, 0);
  }

#pragma unroll
  for (int mi = 0; mi < 2; ++mi)
#pragma unroll
    for (int r = 0; r < 4; ++r) {
      int m = bm + wm * 32 + mi * 16 + quad * 4 + r;
      if (m < M) {
#pragma unroll
        for (int ni = 0; ni < 2; ++ni)
          C[(size_t)m * N + bn + wn * 32 + ni * 16 + l16] = acc[mi][ni][r];
      }
    }
}

// ---------------------------------------------------------------------------
// Fused pack: RoPE + bias-augmented Q/K build + V transpose, per (s-tile, head).
// Qa: [h][s(S_PAD)][160] dense; Ka: [h][s(S_PAD)][168] (DMA-padded rows);
// Vt: [h][d][s(S_PAD)].
// ---------------------------------------------------------------------------
__global__ __launch_bounds__(256) void pack_all(const bf16* __restrict__ qkv,
                                                const int* __restrict__ pos,
                                                const float* __restrict__ bxg,
                                                const float* __restrict__ byg,
                                                const float* __restrict__ bzg,
                                                bf16* __restrict__ Qa,
                                                bf16* __restrict__ Ka,
                                                bf16* __restrict__ Vt) {
  const int st = blockIdx.x, h = blockIdx.y;
  const int t = threadIdx.x;
  __shared__ float bxs[61], bys[61], bzs[17];
  __shared__ float vtile[64][68];

  if (t < 61) { bxs[t] = bxg[t * NH + h]; bys[t] = byg[t * NH + h]; }
  if (t < 17) bzs[t] = bzg[t * NH + h];

  for (int i = t; i < 1024; i += 256) {
    int row = i >> 4, c4 = (i & 15) * 4;
    int sg = min(st * 64 + row, S_LEN - 1);
    bf16x4 v = *(const bf16x4*)&qkv[(size_t)sg * QKV_STRIDE + 2 * DM + h * HDIM + c4];
    *(float4*)&vtile[row][c4] = make_float4((float)v[0], (float)v[1], (float)v[2], (float)v[3]);
  }
  __syncthreads();

  for (int i = t; i < 2048; i += 256) {
    const int sl = i >> 5, sub = i & 31;
    const int s = st * 64 + sl;
    const int sc = min(s, S_LEN - 1);
    const int px = pos[sc * 3 + 0], py = pos[sc * 3 + 1], pz = pos[sc * 3 + 2];
    int j, P, pp;
    if (sub < 10)      { j = sub;      P = 10; pp = min(max(px, 0), 31); }
    else if (sub < 20) { j = sub - 10; P = 10; pp = min(max(py, 0), 31); }
    else               { j = sub - 20; P = 12; pp = min(max(pz, 0), 7);  }
    const float inv = __expf(-(float)j / (float)P * 9.210340371976184f);
    const float ang = (float)pp * inv;
    float sn, cs;
    __sincosf(ang, &sn, &cs);
    const size_t base = (size_t)sc * QKV_STRIDE + h * HDIM + 2 * sub;
    bf16x2 q2 = *(const bf16x2*)&qkv[base];
    bf16x2 k2 = *(const bf16x2*)&qkv[base + DM];
    float q0 = (float)q2[0], q1 = (float)q2[1];
    float k0 = (float)k2[0], k1 = (float)k2[1];
    const size_t qb = ((size_t)h * S_PAD + s) * AUGD;
    const size_t kb = ((size_t)h * S_PAD + s) * KA_STR;
    bf16x2 oq, ok;
    oq[0] = (bf16)((q0 * cs - q1 * sn) * 0.125f);
    oq[1] = (bf16)((q1 * cs + q0 * sn) * 0.125f);
    ok[0] = (bf16)(k0 * cs - k1 * sn);
    ok[1] = (bf16)(k1 * cs + k0 * sn);
    *(bf16x2*)&Qa[qb + 2 * sub] = oq;
    *(bf16x2*)&Ka[kb + 2 * sub] = ok;

    const int ix = min(max(px - sub, -30), 30) + 30;
    const int iy = min(max(py - sub, -30), 30) + 30;
    const int iz = min(max(pz - sub, -8), 8) + 8;
    Qa[qb + 64 + sub]  = (bf16)bxs[ix];
    Qa[qb + 96 + sub]  = (bf16)bys[iy];
    Qa[qb + 128 + sub] = (bf16)bzs[iz];
    Ka[kb + 64 + sub]  = (bf16)(sub == px ? 1.0f : 0.0f);
    Ka[kb + 96 + sub]  = (bf16)(sub == py ? 1.0f : 0.0f);
    Ka[kb + 128 + sub] = (bf16)(sub == pz ? 1.0f : 0.0f);
  }

  for (int i = t; i < 1024; i += 256) {
    int d = i >> 4, s4 = (i & 15) * 4;
    bf16x4 o;
    o[0] = (bf16)vtile[s4 + 0][d];
    o[1] = (bf16)vtile[s4 + 1][d];
    o[2] = (bf16)vtile[s4 + 2][d];
    o[3] = (bf16)vtile[s4 + 3][d];
    *(bf16x4*)&Vt[((size_t)h * HDIM + d) * S_PAD + st * 64 + s4] = o;
  }
}

// ---------------------------------------------------------------------------
// Persistent split-K MFMA attention, S^T formulation. Grid = 1024 blocks
// (4/CU), XCD-pinned heads (h = b & 15). QK^T computed as S^T = K.Q^T;
// S^T's C-layout IS the B-fragment of a K=16 MFMA, so exp'd P feeds PV
// (O^T = V^T.P^T) straight from registers -- no P LDS round-trip, no fences
// (combine ordering comes from the kernel boundary; fused variants regressed
// via VGPR-cap spill (R10) and device-fence L2-flush storm (R11)).
// ---------------------------------------------------------------------------
__global__ __launch_bounds__(256) void attn_split(const bf16* __restrict__ Qa,
                                                  const bf16* __restrict__ Ka,
                                                  const bf16* __restrict__ Vt,
                                                  bf16* __restrict__ outb,
                                                  bf16* __restrict__ Opart,
                                                  float* __restrict__ lpart) {
  const int b = blockIdx.x;
  const int h = b & 15;            // XCD pin: b%8 == h%8
  const int id = 63 - (b >> 4);
  int qt = 14;
  while (QT_BASE[qt] > id) --qt;
  const int c = id - QT_BASE[qt];
  const int chain = 2 * qt + 2;
  const int k0 = c * CHUNK;
  const int kend = min(k0 + CHUNK, chain);

  const int t = threadIdx.x, w = t >> 6, l = t & 63;
  const int quad = l >> 4, l16 = l & 15;

  __shared__ bf16 Ks[64][KA_STR];  // 64 keys x 160(+8 pad) aug dims
  __shared__ bf16 Vs[64][72];      // [dim][key]

  // Q fragments (B-operand of S^T = K.Q^T)
  bf16x8 bq[2][5];
  int igm[2];
#pragma unroll
  for (int mi = 0; mi < 2; ++mi) {
    const int qrow = qt * 128 + w * 32 + mi * 16 + l16;
    igm[mi] = qrow;
    const bf16* qp = &Qa[((size_t)h * S_PAD + qrow) * AUGD + quad * 8];
#pragma unroll
    for (int sg = 0; sg < 5; ++sg) bq[mi][sg] = *(const bf16x8*)(qp + sg * 32);
  }

  f32x4 O[2][4];   // O^T: row = d (quad*4+r within di*16), col = qrow (l16)
#pragma unroll
  for (int mi = 0; mi < 2; ++mi)
#pragma unroll
    for (int di = 0; di < 4; ++di) O[mi][di] = 0;
  float lacc[2] = {0.f, 0.f};

  bf16* KsF = &Ks[0][0];

  for (int kt = k0; kt < kend; ++kt) {
    __syncthreads();
    // async DMA: K-tile = 64 rows x 336 B = 21504 contiguous bytes
    {
      const bf16* gtile = &Ka[((size_t)h * S_PAD + kt * 64) * KA_STR];
#pragma unroll
      for (int seg = 0; seg < 6; ++seg) {
        int sidx = w + seg * 4;
        if (sidx < 21) dma16(gtile + sidx * 512 + l * 8, KsF + sidx * 512);
      }
    }
    for (int i = t; i < 512; i += 256) {
      int row = i >> 3, c8 = (i & 7) * 8;
      *(bf16x8*)&Vs[row][c8] =
          *(const bf16x8*)&Vt[((size_t)h * HDIM + row) * S_PAD + kt * 64 + c8];
    }
    __syncthreads();

    // ---- S^T = K Q^T (includes bias); C: col=qrow(l16), row=key(quad*4+r)
    f32x4 sf[2][4];
#pragma unroll
    for (int ni = 0; ni < 4; ++ni) {
      bf16x8 ak[5];
      const bf16* kp = &Ks[ni * 16 + l16][quad * 8];
#pragma unroll
      for (int sg = 0; sg < 5; ++sg) ak[sg] = *(const bf16x8*)(kp + sg * 32);
#pragma unroll
      for (int mi = 0; mi < 2; ++mi) {
        f32x4 z = {0.f, 0.f, 0.f, 0.f};
#pragma unroll
        for (int sg = 0; sg < 5; ++sg) z = MFMA_BF16(ak[sg], bq[mi][sg], z, 0, 0, 0);
        sf[mi][ni] = z;
      }
    }

    // ---- exp + causal mask, packed directly into PV B-fragments ----
    short4v pf[2][4];
#pragma unroll
    for (int mi = 0; mi < 2; ++mi)
#pragma unroll
      for (int ni = 0; ni < 4; ++ni) {
        bf16x4 pb;
#pragma unroll
        for (int r = 0; r < 4; ++r) {
          const int key = kt * 64 + ni * 16 + quad * 4 + r;
          float p = __expf(sf[mi][ni][r]);
          if (key > igm[mi]) p = 0.f;
          lacc[mi] += p;
          pb[r] = (bf16)p;
        }
        pf[mi][ni] = as_s4(pb);
      }

    // ---- O^T += V^T P^T  (16x16x16 MFMA; A=V frag, B=P frag, all in regs)
#pragma unroll
    for (int g = 0; g < 4; ++g)
#pragma unroll
      for (int di = 0; di < 4; ++di) {
        short4v vf = as_s4(*(const bf16x4*)&Vs[di * 16 + l16][g * 16 + quad * 4]);
#pragma unroll
        for (int mi = 0; mi < 2; ++mi)
          O[mi][di] = MFMA_BF16_K16(vf, pf[mi][g], O[mi][di], 0, 0, 0);
      }
  }

  // l: sum across the 4 quads holding the same qrow
#pragma unroll
  for (int mi = 0; mi < 2; ++mi) {
    float v = lacc[mi];
    v += __shfl_xor(v, 16);
    v += __shfl_xor(v, 32);
    lacc[mi] = v;
  }

  if (k0 == 0 && kend == chain) {
    // single chunk (qt <= 1): finalize directly
#pragma unroll
    for (int mi = 0; mi < 2; ++mi) {
      const int qrow = igm[mi];
      if (qrow < S_LEN) {
        const float inv = 1.0f / lacc[mi];
#pragma unroll
        for (int di = 0; di < 4; ++di) {
          bf16x4 o;
#pragma unroll
          for (int r = 0; r < 4; ++r) o[r] = (bf16)(O[mi][di][r] * inv);
          *(bf16x4*)&outb[(size_t)qrow * DM + h * HDIM + di * 16 + quad * 4] = o;
        }
      }
    }
  } else {
    bf16* ob = Opart + (((size_t)h * NQMULTI + (qt - 2)) * MAXC + c) * 8192;
#pragma unroll
    for (int mi = 0; mi < 2; ++mi) {
      const int row32 = w * 32 + mi * 16 + l16;
#pragma unroll
      for (int di = 0; di < 4; ++di) {
        bf16x4 o;
#pragma unroll
        for (int r = 0; r < 4; ++r) o[r] = (bf16)O[mi][di][r];
        *(bf16x4*)&ob[row32 * 64 + di * 16 + quad * 4] = o;
      }
    }
    if (quad == 0) {
      float* lb = lpart + (((size_t)h * NQMULTI + (qt - 2)) * MAXC + c) * 128;
#pragma unroll
      for (int mi = 0; mi < 2; ++mi) lb[w * 32 + mi * 16 + l16] = lacc[mi];
    }
  }
}

// ---------------------------------------------------------------------------
// Combine split-K partials (bf16 partials, fp32 accumulate), qt >= 2.
// ---------------------------------------------------------------------------
__global__ __launch_bounds__(256) void attn_combine(const bf16* __restrict__ Opart,
                                                    const float* __restrict__ lpart,
                                                    bf16* __restrict__ outb) {
  const int qt = blockIdx.x + 2;
  const int h = blockIdx.y;
  const int t = threadIdx.x;
  const int row = t >> 1, half = t & 1;
  const int nchunk = (2 * qt + 5) >> 2;
  float acc[32];
#pragma unroll
  for (int j = 0; j < 32; ++j) acc[j] = 0.f;
  float lsum = 0.f;
  const size_t pb = ((size_t)h * NQMULTI + (qt - 2)) * MAXC;
  for (int cc = 0; cc < nchunk; ++cc) {
    const bf16x8* p8 = (const bf16x8*)(Opart + (pb + cc) * 8192 + row * 64 + half * 32);
#pragma unroll
    for (int j = 0; j < 4; ++j) {
      bf16x8 v = p8[j];
#pragma unroll
      for (int e = 0; e < 8; ++e) acc[j * 8 + e] += (float)v[e];
    }
    lsum += lpart[(pb + cc) * 128 + row];
  }
  const int s = qt * 128 + row;
  if (s < S_LEN) {
    const float inv = 1.0f / lsum;
    bf16* op = outb + (size_t)s * DM + h * HDIM + half * 32;
#pragma unroll
    for (int j = 0; j < 8; ++j) {
      bf16x4 o;
      o[0] = (bf16)(acc[j * 4 + 0] * inv);
      o[1] = (bf16)(acc[j * 4 + 1] * inv);
      o[2] = (bf16)(acc[j * 4 + 2] * inv);
      o[3] = (bf16)(acc[j * 4 + 3] * inv);
      *(bf16x4*)&op[j * 4] = o;
    }
  }
}

// ---------------------------------------------------------------------------
extern "C" void kernel_launch(void* const* d_in, const int* in_sizes, int n_in,
                              void* d_out, int out_size, void* d_ws, size_t ws_size,
                              hipStream_t stream) {
  const float* x    = (const float*)d_in[0];
  const float* Wqkv = (const float*)d_in[1];
  const float* Wout = (const float*)d_in[2];
  const float* bx   = (const float*)d_in[3];
  const float* by   = (const float*)d_in[4];
  const float* bz   = (const float*)d_in[5];
  const int*   pos  = (const int*)d_in[6];
  float* out = (float*)d_out;

  // Workspace overlay: Opart (27.3 MB bf16) reuses xb/wqkvb/qkvb (21.5 MB,
  // all dead by the time attn_split runs).
  char* ws = (char*)d_ws;
  bf16* Opart = (bf16*)ws;
  bf16* xb    = (bf16*)ws;
  bf16* wqkvb = xb + (size_t)S_LEN * DM;
  bf16* qkvb  = wqkvb + (size_t)QKV_STRIDE * DM;
  ws += (size_t)NH * NQMULTI * MAXC * 8192 * 2;
  bf16* woutb = (bf16*)ws;   ws += (size_t)DM * DM * 2;
  bf16* Qaug  = (bf16*)ws;   ws += (size_t)NH * S_PAD * AUGD * 2;
  bf16* Kaug  = (bf16*)ws;   ws += (size_t)NH * S_PAD * KA_STR * 2;
  bf16* Vtb   = (bf16*)ws;   ws += (size_t)NH * S_PAD * HDIM * 2;
  bf16* attnb = (bf16*)ws;   ws += (size_t)S_LEN * DM * 2;
  float* lpart = (float*)ws; ws += (size_t)NH * NQMULTI * MAXC * 128 * 4;

  const int na4 = S_LEN * DM / 4, nb4 = QKV_STRIDE * DM / 4, nc4 = DM * DM / 4;
  const int ntot = na4 + nb4 + nc4;
  cvt3<<<dim3((ntot + 255) / 256), 256, 0, stream>>>(x, xb, na4, Wqkv, wqkvb, nb4, Wout, woutb, nc4);
  gemm_bt<bf16><<<dim3(QKV_STRIDE / 64, NQT128), 256, 0, stream>>>(
      xb, wqkvb, qkvb, S_LEN, QKV_STRIDE, DM);
  pack_all<<<dim3(S_PAD / 64, NH), 256, 0, stream>>>(qkvb, pos, bx, by, bz, Qaug, Kaug, Vtb);
  attn_split<<<dim3(NH * NCHUNK_HEAD), 256, 0, stream>>>(Qaug, Kaug, Vtb, attnb, Opart, lpart);
  attn_combine<<<dim3(NQMULTI, NH), 256, 0, stream>>>(Opart, lpart, attnb);
  gemm_bt64<<<dim3(DM / 64, (S_LEN + 63) / 64), 256, 0, stream>>>(
      attnb, woutb, out, S_LEN, DM, DM);
}